// Round 4
// baseline (118.754 us; speedup 1.0000x reference)
//
#include <hip/hip_runtime.h>

#define BATCH 8192
#define IN_DIM 512
#define NT 64
#define NI 31
#define NL 32
#define ODIM 16
#define NPAD (NT*NL)   // 2048 padded GEMM columns

typedef __attribute__((ext_vector_type(8))) short bf16x8;
typedef __attribute__((ext_vector_type(4))) float f32x4;

__device__ __forceinline__ unsigned short f2b(float f) {
  union { float f; unsigned int u; } v; v.f = f;
  unsigned int r = v.u + 0x7fffu + ((v.u >> 16) & 1u);   // RNE
  return (unsigned short)(r >> 16);
}
__device__ __forceinline__ float b2f(unsigned short h) {
  union { unsigned int u; float f; } v; v.u = ((unsigned int)h) << 16;
  return v.f;
}
__device__ __forceinline__ unsigned int cvtpk(float lo, float hi) {
  unsigned int r;
  asm("v_cvt_pk_bf16_f32 %0, %1, %2" : "=v"(r) : "v"(lo), "v"(hi));
  return r;
}

// ---------------------------------------------------------------------------
// prep (small now): W fp32 -> bf16 with 16B-granule XOR swizzle (slot g of
// each 32-K window holds source granule g ^ ((row>>1)&3)); leaf softmax
// * (1/NT); zero `out`. x conversion moved INTO fused (A-panel reg-staging).
// ---------------------------------------------------------------------------
__global__ __launch_bounds__(256) void prep_kernel(
    const float* __restrict__ W, const float* __restrict__ leafs,
    unsigned short* __restrict__ wb, float* __restrict__ lsm,
    float* __restrict__ out)
{
  const int NWg = NPAD * (IN_DIM/8);    // 131072 granules of 8
  const int NS  = NT*NL;                // 2048 leaf rows
  const int NZ  = BATCH*ODIM/4;         // 32768 float4 zero tasks
  int gid = blockIdx.x*256 + threadIdx.x;
  if (gid < NWg) {
    int row = gid >> 6, k8 = gid & 63;
    int t = row >> 5, i = row & 31;
    int kt = k8 >> 2, g = k8 & 3;
    int gs = g ^ ((row >> 1) & 3);
    ushort4 o0, o1;
    if (i == 31) { o0.x=o0.y=o0.z=o0.w=0; o1=o0; }
    else {
      const float* s = W + (size_t)(t*NI+i)*IN_DIM + kt*32 + gs*8;
      float4 v0 = ((const float4*)s)[0], v1 = ((const float4*)s)[1];
      o0.x=f2b(v0.x); o0.y=f2b(v0.y); o0.z=f2b(v0.z); o0.w=f2b(v0.w);
      o1.x=f2b(v1.x); o1.y=f2b(v1.y); o1.z=f2b(v1.z); o1.w=f2b(v1.w);
    }
    ((ushort4*)wb)[gid*2]   = o0;
    ((ushort4*)wb)[gid*2+1] = o1;
  } else if ((gid -= NWg) < NS) {
    const float* src = leafs + (size_t)gid*ODIM;
    float m = src[0];
    #pragma unroll
    for (int o=1;o<ODIM;++o) m = fmaxf(m, src[o]);
    float e[ODIM]; float s = 0.f;
    #pragma unroll
    for (int o=0;o<ODIM;++o) { e[o] = __expf(src[o]-m); s += e[o]; }
    float inv = 1.f/(s*(float)NT);
    #pragma unroll
    for (int o=0;o<ODIM;++o) lsm[(size_t)gid*ODIM+o] = e[o]*inv;
  } else if ((gid -= NS) < NZ) {
    float4 zero = {0.f,0.f,0.f,0.f};
    ((float4*)out)[gid] = zero;
  }
}

// ---------------------------------------------------------------------------
// fused: bf16 GEMM (M=8192,N=2048,K=512) tile 256x128 + sigmoid + route
// expansion + SECOND MFMA (routes[256x128] @ lsm_slice[128x16]).
// 4 waves, wave-tile 128x64.
// Staging: A-panel converted from fp32 x IN-KERNEL: per K-step each thread
// owns one LDS row (tid), loads 8x dwordx4 one K-step AHEAD (regs held
// across the MFMA cluster to hide latency), cvt_pk -> 4x ds_write_b128 at
// XOR-swizzled slots. B via wb + global_load_lds (2 instr/wave), issued
// right after the barrier; sched_barrier(0) pins issue order so the head
// vmcnt(8) waits exactly the 2 B-gloads of tile kt (A-loads of kt+1 fly on).
// 2-stage LDS (24576 shorts); epilogue overlay Pt[256][132] / Rt[256][136].
// Output: atomicAdd into zeroed out (16 column-block partials per element).
// ---------------------------------------------------------------------------
__device__ __forceinline__ void async16(const unsigned short* g, unsigned short* l) {
  __builtin_amdgcn_global_load_lds(
      (const __attribute__((address_space(1))) unsigned int*)g,
      (__attribute__((address_space(3))) unsigned int*)l,
      16, 0, 0);
}

#define SSTG 12288         // shorts per stage: A 256*32=8192 + B 128*32=4096

__global__ __launch_bounds__(256, 2) void fused_kernel(
    const float* __restrict__ x, const unsigned short* __restrict__ wb,
    const float* __restrict__ bias, const float* __restrict__ lsm,
    float* __restrict__ out)
{
  // max(staging 2*12288=24576, Pt 256*132=33792, Rt 256*136=34816) shorts
  __shared__ __align__(16) unsigned short smem[34816];   // 69632 B -> 2 blocks/CU

  const int tid  = threadIdx.x;
  const int lane = tid & 63;
  const int wave = tid >> 6;
  const int wm = wave & 1, wn = wave >> 1;   // wave-tile: M 128, N 64

  // XCD-aware block swizzle
  const int bid = blockIdx.x;
  const int m_t = (bid & 7)*4 + (bid >> 7);      // 0..31
  const int n_t = (bid >> 3) & 15;               // 0..15
  const int m0 = m_t * 256, n0 = n_t * 128;

  f32x4 acc[8][4];
  #pragma unroll
  for (int i=0;i<8;++i)
    #pragma unroll
    for (int j=0;j<4;++j) { f32x4 z = {0.f,0.f,0.f,0.f}; acc[i][j] = z; }

  // B staging source (prep-swizzled wb, global_load_lds path)
  const int srow = lane >> 2, scol = (lane & 3) * 8;
  const unsigned short* gbw = wb + (size_t)(n0 + wave*32 + srow)*IN_DIM + scol;

  // A staging source: thread owns LDS A row == tid == global row m0+tid
  const float4* gx4 = (const float4*)(x + (size_t)(m0 + tid)*IN_DIM);
  const int aswz = (tid >> 1) & 3;              // row-swizzle term for writes

  const int l15 = lane & 15, quad = lane >> 4;
  const int cs   = (quad ^ ((l15 >> 1) & 3)) << 3;   // swizzled K-granule offset

  float4 L[8];                                   // in-flight A fp32 (32 VGPR)

  // ---- prologue: stage tile 0, then issue A(1) loads ----
  #pragma unroll
  for (int j=0;j<8;++j) L[j] = gx4[j];           // A(0)
  {
    unsigned short* Ad = smem + tid*32;
    #pragma unroll
    for (int gsrc=0; gsrc<4; ++gsrc) {
      uint4 w;
      w.x = cvtpk(L[2*gsrc].x, L[2*gsrc].y);
      w.y = cvtpk(L[2*gsrc].z, L[2*gsrc].w);
      w.z = cvtpk(L[2*gsrc+1].x, L[2*gsrc+1].y);
      w.w = cvtpk(L[2*gsrc+1].z, L[2*gsrc+1].w);
      *(uint4*)(Ad + (gsrc ^ aswz)*8) = w;
    }
  }
  #pragma unroll
  for (int c=0;c<2;++c) async16(gbw + c*16*IN_DIM, smem + 8192 + wave*1024 + c*512);
  __builtin_amdgcn_sched_barrier(0);
  #pragma unroll
  for (int j=0;j<8;++j) L[j] = gx4[8 + j];       // A(1) in flight

  for (int kt = 0; kt < 15; ++kt) {
    unsigned short* stc = smem + (kt & 1) * SSTG;
    unsigned short* stn = smem + ((kt + 1) & 1) * SSTG;
    // outstanding here: B(kt)x2 [oldest], A(kt+1)x8 -> vmcnt(8) waits B(kt).
    asm volatile("s_waitcnt vmcnt(8) lgkmcnt(0)" ::: "memory");
    __builtin_amdgcn_s_barrier();
    // issue B(kt+1) -> stn (stage was fully read last iter; barrier passed)
    #pragma unroll
    for (int c=0;c<2;++c)
      async16(gbw + (kt+1)*32 + c*16*IN_DIM, stn + 8192 + wave*1024 + c*512);
    __builtin_amdgcn_sched_barrier(0);   // pin issue order: B(kt+1) before A(kt+2)

    const unsigned short* As = stc;
    const unsigned short* Bs = stc + 8192;
    bf16x8 af[8], bfr[4];
    #pragma unroll
    for (int mi=0;mi<8;++mi)
      af[mi] = *(const bf16x8*)(As + (wm*128 + mi*16 + l15)*32 + cs);
    #pragma unroll
    for (int ni=0;ni<4;++ni)
      bfr[ni] = *(const bf16x8*)(Bs + (wn*64 + ni*16 + l15)*32 + cs);
    __builtin_amdgcn_s_setprio(1);
    #pragma unroll
    for (int mi=0;mi<8;++mi)
      #pragma unroll
      for (int ni=0;ni<4;++ni)
        acc[mi][ni] = __builtin_amdgcn_mfma_f32_16x16x32_bf16(
            af[mi], bfr[ni], acc[mi][ni], 0, 0, 0);
    __builtin_amdgcn_s_setprio(0);

    // stage A(kt+1): compiler auto-waits vmcnt for L uses (A older than B(kt+1))
    {
      unsigned short* Ad = stn + tid*32;
      #pragma unroll
      for (int gsrc=0; gsrc<4; ++gsrc) {
        uint4 w;
        w.x = cvtpk(L[2*gsrc].x, L[2*gsrc].y);
        w.y = cvtpk(L[2*gsrc].z, L[2*gsrc].w);
        w.z = cvtpk(L[2*gsrc+1].x, L[2*gsrc+1].y);
        w.w = cvtpk(L[2*gsrc+1].z, L[2*gsrc+1].w);
        *(uint4*)(Ad + (gsrc ^ aswz)*8) = w;
      }
    }
    if (kt < 14) {                        // issue A(kt+2) into L
      #pragma unroll
      for (int j=0;j<8;++j) L[j] = gx4[(kt+2)*8 + j];
    }
  }
  // peeled final K-step (tile 15, stage 15&1 = st1)
  asm volatile("s_waitcnt vmcnt(0) lgkmcnt(0)" ::: "memory");
  __builtin_amdgcn_s_barrier();
  {
    const unsigned short* As = smem + SSTG;
    const unsigned short* Bs = smem + SSTG + 8192;
    bf16x8 af[8], bfr[4];
    #pragma unroll
    for (int mi=0;mi<8;++mi)
      af[mi] = *(const bf16x8*)(As + (wm*128 + mi*16 + l15)*32 + cs);
    #pragma unroll
    for (int ni=0;ni<4;++ni)
      bfr[ni] = *(const bf16x8*)(Bs + (wn*64 + ni*16 + l15)*32 + cs);
    __builtin_amdgcn_s_setprio(1);
    #pragma unroll
    for (int mi=0;mi<8;++mi)
      #pragma unroll
      for (int ni=0;ni<4;++ni)
        acc[mi][ni] = __builtin_amdgcn_mfma_f32_16x16x32_bf16(
            af[mi], bfr[ni], acc[mi][ni], 0, 0, 0);
    __builtin_amdgcn_s_setprio(0);
  }

  // lsm B-frags for the second MFMA: lane(l15=n, quad) elem j = bf16 of
  // lsm[(t0+s)*32 + quad*8 + j][n]  (kstep s == tree s of this block)
  bf16x8 bleaf[4];
  {
    const int t0 = n_t * 4;
    #pragma unroll
    for (int s=0;s<4;++s) {
      union { bf16x8 v; unsigned short u[8]; } tmp;
      #pragma unroll
      for (int j=0;j<8;++j)
        tmp.u[j] = f2b(lsm[((size_t)(t0+s)*NL + quad*8 + j)*ODIM + l15]);
      bleaf[s] = tmp.v;
    }
  }

  __syncthreads();   // full drain: staging reads done before Pt overlays staging

  // Phase A: bias + sigmoid -> Pt[256][132] bf16 (rows 264 B, 8B-aligned)
  unsigned short* Pt = smem;
  #pragma unroll
  for (int ni=0;ni<4;++ni) {
    int cl = wn*64 + ni*16 + l15;          // local col 0..127
    int gcol = n0 + cl;
    int tt = gcol >> 5, ii = gcol & 31;
    float bv = (ii < NI) ? bias[tt*NI + ii] : 0.f;
    #pragma unroll
    for (int mi=0;mi<8;++mi) {
      int lrow = wm*128 + mi*16 + quad*4;
      #pragma unroll
      for (int r=0;r<4;++r) {
        float v = acc[mi][ni][r] + bv;
        Pt[(lrow + r)*132 + cl] = f2b(1.f/(1.f + __expf(-v)));
      }
    }
  }
  __syncthreads();

  // Phase B: thread=row expands 4 trees' routes into 64 packed bf16 pairs.
  const int row = tid;
  unsigned int rt[64];
  #pragma unroll
  for (int tl=0; tl<4; ++tl) {
    const short4* pr4 = (const short4*)(Pt + row*132 + tl*32);
    union { short4 v4[8]; unsigned short u[32]; } qb;
    #pragma unroll
    for (int c=0;c<8;++c) qb.v4[c] = pr4[c];
    float q[31];
    #pragma unroll
    for (int i=0;i<31;++i) q[i] = b2f(qb.u[i]);
    float v[32];
    v[0] = q[0]; v[1] = 1.f - q[0];
    #pragma unroll
    for (int d=1; d<=4; ++d) {
      const int s = 1 << d;
      #pragma unroll
      for (int j=s-1; j>=0; --j) {
        float pj = q[(s-1)+j];
        float base = v[j];
        v[2*j]   = base * pj;
        v[2*j+1] = base * (1.f - pj);
      }
    }
    #pragma unroll
    for (int k=0;k<16;++k)
      rt[tl*16+k] = (unsigned int)f2b(v[2*k]) | ((unsigned int)f2b(v[2*k+1]) << 16);
  }
  __syncthreads();   // all Pt reads done before Rt overwrites

  // write Rt[256][136] bf16 (rows 272 B, 16B-aligned); own row, 16x b128
  unsigned int* Rt32 = (unsigned int*)smem;
  {
    uint4* dst = (uint4*)(Rt32 + row*68);
    #pragma unroll
    for (int c=0;c<16;++c) {
      uint4 w; w.x=rt[c*4]; w.y=rt[c*4+1]; w.z=rt[c*4+2]; w.w=rt[c*4+3];
      dst[c] = w;
    }
  }
  __syncthreads();

  // second MFMA: routes[256x128] @ lsm[128x16]; wave covers mtiles 4w..4w+3;
  // accumulate into out via device-scope fp32 atomics (16 partials/elem).
  const unsigned short* RtS = smem;
  #pragma unroll
  for (int mt=0; mt<4; ++mt) {
    const int mrow = (wave*4 + mt)*16;
    f32x4 a2 = {0.f,0.f,0.f,0.f};
    #pragma unroll
    for (int s=0;s<4;++s) {
      bf16x8 af2 = *(const bf16x8*)(RtS + (mrow + l15)*136 + s*32 + quad*8);
      a2 = __builtin_amdgcn_mfma_f32_16x16x32_bf16(af2, bleaf[s], a2, 0, 0, 0);
    }
    // C/D: col=l15 (ODIM), row=quad*4+r
    float* op = out + (size_t)(m0 + mrow + quad*4)*ODIM + l15;
    #pragma unroll
    for (int r=0;r<4;++r)
      atomicAdd(op + r*ODIM, a2[r]);
  }
}

// ---------------------------------------------------------------------------
extern "C" void kernel_launch(void* const* d_in, const int* in_sizes, int n_in,
                              void* d_out, int out_size, void* d_ws, size_t ws_size,
                              hipStream_t stream) {
  const float* x     = (const float*)d_in[0];
  const float* W     = (const float*)d_in[1];
  const float* b     = (const float*)d_in[2];
  const float* leafs = (const float*)d_in[3];
  float* out = (float*)d_out;

  char* ws = (char*)d_ws;
  unsigned short* wb  = (unsigned short*)ws;                       // 2,097,152 B
  float*          lsm = (float*)(ws + 2097152);                    //   131,072 B

  const int total = NPAD*(IN_DIM/8) + NT*NL + BATCH*ODIM/4;        // 165888
  prep_kernel<<<dim3((total + 255)/256), dim3(256), 0, stream>>>(
      W, leafs, wb, lsm, out);
  fused_kernel<<<dim3(512), dim3(256), 0, stream>>>(
      x, wb, b, lsm, out);
}

// Round 5
// 102.404 us; speedup vs baseline: 1.1597x; 1.1597x over previous
//
#include <hip/hip_runtime.h>

#define BATCH 8192
#define IN_DIM 512
#define NT 64
#define NI 31
#define NL 32
#define ODIM 16
#define NPAD (NT*NL)   // 2048 padded GEMM columns

typedef __attribute__((ext_vector_type(8))) short bf16x8;
typedef __attribute__((ext_vector_type(4))) float f32x4;

__device__ __forceinline__ unsigned short f2b(float f) {
  union { float f; unsigned int u; } v; v.f = f;
  unsigned int r = v.u + 0x7fffu + ((v.u >> 16) & 1u);   // RNE
  return (unsigned short)(r >> 16);
}
__device__ __forceinline__ float b2f(unsigned short h) {
  union { unsigned int u; float f; } v; v.u = ((unsigned int)h) << 16;
  return v.f;
}
__device__ __forceinline__ unsigned int cvtpk(float lo, float hi) {
  unsigned int r;
  asm("v_cvt_pk_bf16_f32 %0, %1, %2" : "=v"(r) : "v"(lo), "v"(hi));
  return r;
}

// ---------------------------------------------------------------------------
// prep: W fp32 -> bf16 with 16B-granule XOR swizzle (slot g of each 32-K
// window holds source granule g ^ ((row>>1)&3)); leaf softmax * (1/NT);
// zero `out`. x conversion lives inside fused (coalesced reg-staging).
// ---------------------------------------------------------------------------
__global__ __launch_bounds__(256) void prep_kernel(
    const float* __restrict__ W, const float* __restrict__ leafs,
    unsigned short* __restrict__ wb, float* __restrict__ lsm,
    float* __restrict__ out)
{
  const int NWg = NPAD * (IN_DIM/8);    // 131072 granules of 8
  const int NS  = NT*NL;                // 2048 leaf rows
  const int NZ  = BATCH*ODIM/4;         // 32768 float4 zero tasks
  int gid = blockIdx.x*256 + threadIdx.x;
  if (gid < NWg) {
    int row = gid >> 6, k8 = gid & 63;
    int t = row >> 5, i = row & 31;
    int kt = k8 >> 2, g = k8 & 3;
    int gs = g ^ ((row >> 1) & 3);
    ushort4 o0, o1;
    if (i == 31) { o0.x=o0.y=o0.z=o0.w=0; o1=o0; }
    else {
      const float* s = W + (size_t)(t*NI+i)*IN_DIM + kt*32 + gs*8;
      float4 v0 = ((const float4*)s)[0], v1 = ((const float4*)s)[1];
      o0.x=f2b(v0.x); o0.y=f2b(v0.y); o0.z=f2b(v0.z); o0.w=f2b(v0.w);
      o1.x=f2b(v1.x); o1.y=f2b(v1.y); o1.z=f2b(v1.z); o1.w=f2b(v1.w);
    }
    ((ushort4*)wb)[gid*2]   = o0;
    ((ushort4*)wb)[gid*2+1] = o1;
  } else if ((gid -= NWg) < NS) {
    const float* src = leafs + (size_t)gid*ODIM;
    float m = src[0];
    #pragma unroll
    for (int o=1;o<ODIM;++o) m = fmaxf(m, src[o]);
    float e[ODIM]; float s = 0.f;
    #pragma unroll
    for (int o=0;o<ODIM;++o) { e[o] = __expf(src[o]-m); s += e[o]; }
    float inv = 1.f/(s*(float)NT);
    #pragma unroll
    for (int o=0;o<ODIM;++o) lsm[(size_t)gid*ODIM+o] = e[o]*inv;
  } else if ((gid -= NS) < NZ) {
    float4 zero = {0.f,0.f,0.f,0.f};
    ((float4*)out)[gid] = zero;
  }
}

// ---------------------------------------------------------------------------
// fused: bf16 GEMM (M=8192,N=2048,K=512) tile 256x128 + sigmoid + route
// expansion + SECOND MFMA (routes[256x128] @ lsm_slice[128x16]).
// 4 waves, wave-tile 128x64.
// A staging (in-kernel fp32->bf16), COALESCED: lane l owns 8 row-segments
// row = wave*64 + j*8 + (l>>3), 16B at float-col (l&7)*4 — 8 lanes cover
// 128B contiguous per row (8 wide transactions/instr, vs 64 in the
// per-thread-row mapping that regressed round 4). Loads issued one K-step
// ahead (held in 32 VGPR across MFMA cluster); cvt_pk -> 8x ds_write_b64
// at lane-static XOR-swizzled offsets (slot = ((l&7)>>1) ^ ((l>>4)&3),
// identical layout to prep's g ^ ((row>>1)&3); conflict-free).
// B via wb + global_load_lds, issued right after the barrier; vmcnt(8)
// at loop head waits exactly the 2 B-gloads of tile kt.
// 2-stage LDS (24576 shorts); epilogue overlay Pt[256][132] / Rt[256][136].
// Output: atomicAdd into zeroed out (16 column-block partials per element).
// ---------------------------------------------------------------------------
__device__ __forceinline__ void async16(const unsigned short* g, unsigned short* l) {
  __builtin_amdgcn_global_load_lds(
      (const __attribute__((address_space(1))) unsigned int*)g,
      (__attribute__((address_space(3))) unsigned int*)l,
      16, 0, 0);
}

#define SSTG 12288         // shorts per stage: A 256*32=8192 + B 128*32=4096

__global__ __launch_bounds__(256, 2) void fused_kernel(
    const float* __restrict__ x, const unsigned short* __restrict__ wb,
    const float* __restrict__ bias, const float* __restrict__ lsm,
    float* __restrict__ out)
{
  // max(staging 2*12288=24576, Pt 256*132=33792, Rt 256*136=34816) shorts
  __shared__ __align__(16) unsigned short smem[34816];   // 69632 B -> 2 blocks/CU

  const int tid  = threadIdx.x;
  const int lane = tid & 63;
  const int wave = tid >> 6;
  const int wm = wave & 1, wn = wave >> 1;   // wave-tile: M 128, N 64

  // XCD-aware block swizzle
  const int bid = blockIdx.x;
  const int m_t = (bid & 7)*4 + (bid >> 7);      // 0..31
  const int n_t = (bid >> 3) & 15;               // 0..15
  const int m0 = m_t * 256, n0 = n_t * 128;

  f32x4 acc[8][4];
  #pragma unroll
  for (int i=0;i<8;++i)
    #pragma unroll
    for (int j=0;j<4;++j) { f32x4 z = {0.f,0.f,0.f,0.f}; acc[i][j] = z; }

  // B staging source (prep-swizzled wb, global_load_lds path)
  const int srow = lane >> 2, scol = (lane & 3) * 8;
  const unsigned short* gbw = wb + (size_t)(n0 + wave*32 + srow)*IN_DIM + scol;

  // A staging source: lane l, load j -> row wave*64 + j*8 + (l>>3),
  // float4 index (within row) kt*8 + (l&7)
  const float4* gxA = ((const float4*)x)
      + (size_t)(m0 + wave*64 + (lane>>3))*(IN_DIM/4) + (lane&7);
  // A LDS write offset (shorts), lane-static part; +j*256 per row step
  const int awr = (wave*64 + (lane>>3))*32
                + ((((lane&7)>>1) ^ ((lane>>4)&3))<<3) + (lane&1)*4;

  const int l15 = lane & 15, quad = lane >> 4;
  const int cs   = (quad ^ ((l15 >> 1) & 3)) << 3;   // swizzled K-granule offset

  float4 L[8];                                   // in-flight A fp32 (32 VGPR)

  // ---- prologue: stage tile 0, issue B(0), then A(1) loads ----
  #pragma unroll
  for (int j=0;j<8;++j) L[j] = gxA[(size_t)j*8*(IN_DIM/4)];     // A(0)
  {
    unsigned short* Ad = smem + awr;
    #pragma unroll
    for (int j=0;j<8;++j) {
      uint2 w; w.x = cvtpk(L[j].x, L[j].y); w.y = cvtpk(L[j].z, L[j].w);
      *(uint2*)(Ad + j*256) = w;
    }
  }
  #pragma unroll
  for (int c=0;c<2;++c) async16(gbw + c*16*IN_DIM, smem + 8192 + wave*1024 + c*512);
  __builtin_amdgcn_sched_barrier(0);
  #pragma unroll
  for (int j=0;j<8;++j) L[j] = gxA[(size_t)j*8*(IN_DIM/4) + 8]; // A(1) in flight

  for (int kt = 0; kt < 15; ++kt) {
    unsigned short* stc = smem + (kt & 1) * SSTG;
    unsigned short* stn = smem + ((kt + 1) & 1) * SSTG;
    // outstanding here: B(kt)x2 [oldest], A(kt+1)x8 -> vmcnt(8) waits B(kt).
    asm volatile("s_waitcnt vmcnt(8) lgkmcnt(0)" ::: "memory");
    __builtin_amdgcn_s_barrier();
    // issue B(kt+1) -> stn (stage fully read last iter; barrier passed)
    #pragma unroll
    for (int c=0;c<2;++c)
      async16(gbw + (kt+1)*32 + c*16*IN_DIM, stn + 8192 + wave*1024 + c*512);
    __builtin_amdgcn_sched_barrier(0);   // pin issue order: B(kt+1) before A(kt+2)

    const unsigned short* As = stc;
    const unsigned short* Bs = stc + 8192;
    bf16x8 af[8], bfr[4];
    #pragma unroll
    for (int mi=0;mi<8;++mi)
      af[mi] = *(const bf16x8*)(As + (wm*128 + mi*16 + l15)*32 + cs);
    #pragma unroll
    for (int ni=0;ni<4;++ni)
      bfr[ni] = *(const bf16x8*)(Bs + (wn*64 + ni*16 + l15)*32 + cs);
    __builtin_amdgcn_s_setprio(1);
    #pragma unroll
    for (int mi=0;mi<8;++mi)
      #pragma unroll
      for (int ni=0;ni<4;++ni)
        acc[mi][ni] = __builtin_amdgcn_mfma_f32_16x16x32_bf16(
            af[mi], bfr[ni], acc[mi][ni], 0, 0, 0);
    __builtin_amdgcn_s_setprio(0);

    // stage A(kt+1): compiler auto-waits vmcnt for L uses (A older than B(kt+1))
    {
      unsigned short* Ad = stn + awr;
      #pragma unroll
      for (int j=0;j<8;++j) {
        uint2 w; w.x = cvtpk(L[j].x, L[j].y); w.y = cvtpk(L[j].z, L[j].w);
        *(uint2*)(Ad + j*256) = w;
      }
    }
    if (kt < 14) {                        // issue A(kt+2) into L
      #pragma unroll
      for (int j=0;j<8;++j) L[j] = gxA[(size_t)j*8*(IN_DIM/4) + (kt+2)*8];
    }
  }
  // peeled final K-step (tile 15, stage 15&1 = st1)
  asm volatile("s_waitcnt vmcnt(0) lgkmcnt(0)" ::: "memory");
  __builtin_amdgcn_s_barrier();
  {
    const unsigned short* As = smem + SSTG;
    const unsigned short* Bs = smem + SSTG + 8192;
    bf16x8 af[8], bfr[4];
    #pragma unroll
    for (int mi=0;mi<8;++mi)
      af[mi] = *(const bf16x8*)(As + (wm*128 + mi*16 + l15)*32 + cs);
    #pragma unroll
    for (int ni=0;ni<4;++ni)
      bfr[ni] = *(const bf16x8*)(Bs + (wn*64 + ni*16 + l15)*32 + cs);
    __builtin_amdgcn_s_setprio(1);
    #pragma unroll
    for (int mi=0;mi<8;++mi)
      #pragma unroll
      for (int ni=0;ni<4;++ni)
        acc[mi][ni] = __builtin_amdgcn_mfma_f32_16x16x32_bf16(
            af[mi], bfr[ni], acc[mi][ni], 0, 0, 0);
    __builtin_amdgcn_s_setprio(0);
  }

  // lsm B-frags for the second MFMA: lane(l15=n, quad) elem j = bf16 of
  // lsm[(t0+s)*32 + quad*8 + j][n]  (kstep s == tree s of this block)
  bf16x8 bleaf[4];
  {
    const int t0 = n_t * 4;
    #pragma unroll
    for (int s=0;s<4;++s) {
      union { bf16x8 v; unsigned short u[8]; } tmp;
      #pragma unroll
      for (int j=0;j<8;++j)
        tmp.u[j] = f2b(lsm[((size_t)(t0+s)*NL + quad*8 + j)*ODIM + l15]);
      bleaf[s] = tmp.v;
    }
  }

  __syncthreads();   // full drain: staging reads done before Pt overlays staging

  // Phase A: bias + sigmoid -> Pt[256][132] bf16 (rows 264 B, 8B-aligned)
  unsigned short* Pt = smem;
  #pragma unroll
  for (int ni=0;ni<4;++ni) {
    int cl = wn*64 + ni*16 + l15;          // local col 0..127
    int gcol = n0 + cl;
    int tt = gcol >> 5, ii = gcol & 31;
    float bv = (ii < NI) ? bias[tt*NI + ii] : 0.f;
    #pragma unroll
    for (int mi=0;mi<8;++mi) {
      int lrow = wm*128 + mi*16 + quad*4;
      #pragma unroll
      for (int r=0;r<4;++r) {
        float v = acc[mi][ni][r] + bv;
        Pt[(lrow + r)*132 + cl] = f2b(1.f/(1.f + __expf(-v)));
      }
    }
  }
  __syncthreads();

  // Phase B: thread=row expands 4 trees' routes into 64 packed bf16 pairs.
  const int row = tid;
  unsigned int rt[64];
  #pragma unroll
  for (int tl=0; tl<4; ++tl) {
    const short4* pr4 = (const short4*)(Pt + row*132 + tl*32);
    union { short4 v4[8]; unsigned short u[32]; } qb;
    #pragma unroll
    for (int c=0;c<8;++c) qb.v4[c] = pr4[c];
    float q[31];
    #pragma unroll
    for (int i=0;i<31;++i) q[i] = b2f(qb.u[i]);
    float v[32];
    v[0] = q[0]; v[1] = 1.f - q[0];
    #pragma unroll
    for (int d=1; d<=4; ++d) {
      const int s = 1 << d;
      #pragma unroll
      for (int j=s-1; j>=0; --j) {
        float pj = q[(s-1)+j];
        float base = v[j];
        v[2*j]   = base * pj;
        v[2*j+1] = base * (1.f - pj);
      }
    }
    #pragma unroll
    for (int k=0;k<16;++k)
      rt[tl*16+k] = (unsigned int)f2b(v[2*k]) | ((unsigned int)f2b(v[2*k+1]) << 16);
  }
  __syncthreads();   // all Pt reads done before Rt overwrites

  // write Rt[256][136] bf16 (rows 272 B, 16B-aligned); own row, 16x b128
  unsigned int* Rt32 = (unsigned int*)smem;
  {
    uint4* dst = (uint4*)(Rt32 + row*68);
    #pragma unroll
    for (int c=0;c<16;++c) {
      uint4 w; w.x=rt[c*4]; w.y=rt[c*4+1]; w.z=rt[c*4+2]; w.w=rt[c*4+3];
      dst[c] = w;
    }
  }
  __syncthreads();

  // second MFMA: routes[256x128] @ lsm[128x16]; wave covers mtiles 4w..4w+3;
  // accumulate into out via device-scope fp32 atomics (16 partials/elem).
  const unsigned short* RtS = smem;
  #pragma unroll
  for (int mt=0; mt<4; ++mt) {
    const int mrow = (wave*4 + mt)*16;
    f32x4 a2 = {0.f,0.f,0.f,0.f};
    #pragma unroll
    for (int s=0;s<4;++s) {
      bf16x8 af2 = *(const bf16x8*)(RtS + (mrow + l15)*136 + s*32 + quad*8);
      a2 = __builtin_amdgcn_mfma_f32_16x16x32_bf16(af2, bleaf[s], a2, 0, 0, 0);
    }
    // C/D: col=l15 (ODIM), row=quad*4+r
    float* op = out + (size_t)(m0 + mrow + quad*4)*ODIM + l15;
    #pragma unroll
    for (int r=0;r<4;++r)
      atomicAdd(op + r*ODIM, a2[r]);
  }
}

// ---------------------------------------------------------------------------
extern "C" void kernel_launch(void* const* d_in, const int* in_sizes, int n_in,
                              void* d_out, int out_size, void* d_ws, size_t ws_size,
                              hipStream_t stream) {
  const float* x     = (const float*)d_in[0];
  const float* W     = (const float*)d_in[1];
  const float* b     = (const float*)d_in[2];
  const float* leafs = (const float*)d_in[3];
  float* out = (float*)d_out;

  char* ws = (char*)d_ws;
  unsigned short* wb  = (unsigned short*)ws;                       // 2,097,152 B
  float*          lsm = (float*)(ws + 2097152);                    //   131,072 B

  const int total = NPAD*(IN_DIM/8) + NT*NL + BATCH*ODIM/4;        // 165888
  prep_kernel<<<dim3((total + 255)/256), dim3(256), 0, stream>>>(
      W, leafs, wb, lsm, out);
  fused_kernel<<<dim3(512), dim3(256), 0, stream>>>(
      x, wb, b, lsm, out);
}